// Round 5
// baseline (209.182 us; speedup 1.0000x reference)
//
#include <hip/hip_runtime.h>
#include <hip/hip_bf16.h>

// Problem constants
#define NB    4096      // batch rows
#define IND_  512       // feature dim
#define OUTD_ 512       // output dim (GEMM M, "o")
#define XCOLS 514       // P + IND
#define ND    25        // D^P
#define KTOT  12800     // IND_*ND : big-GEMM K

// GEMM tiling
#define BM 128
#define BN 128
#define BK 64

typedef float  f32x4  __attribute__((ext_vector_type(4)));
typedef __bf16 bf16x8 __attribute__((ext_vector_type(8)));
typedef unsigned short u16x8 __attribute__((ext_vector_type(8)));
typedef unsigned int   u32x4 __attribute__((ext_vector_type(4)));

__device__ __forceinline__ unsigned short f2bf(float f) {
  unsigned int x = __float_as_uint(f);
  return (unsigned short)((x + 0x7fffu + ((x >> 16) & 1u)) >> 16);
}

__device__ __forceinline__ float bf2f(unsigned short u) {
  return __uint_as_float(((unsigned int)u) << 16);
}

__device__ __forceinline__ float basis_f(float t, int j) {
  switch (j) {
    case 0: return 1.0f;
    case 1: return t;
    case 2: return t * t;
    case 3: { float r = t - 0.33f; r = r > 0.0f ? r : 0.0f; return r * r; }
    default:{ float r = t - 0.66f; r = r > 0.0f ? r : 0.0f; return r * r; }
  }
}

__device__ __forceinline__ void gload_lds16(const void* g, void* l) {
  __builtin_amdgcn_global_load_lds(
      (const __attribute__((address_space(1))) void*)g,
      (__attribute__((address_space(3))) void*)l, 16, 0, 0);
}

// pack two scaled fp32 -> bf16 pair (RNE, same as __float22bfloat162_rn)
__device__ __forceinline__ unsigned int pk_bf16(float a, float b) {
  return (unsigned int)f2bf(a) | ((unsigned int)f2bf(b) << 16);
}

// ---------------------------------------------------------------------------
// prep_x: per row b: kb[b][25], XFb[b][i] (bf16), out[b][0:2] = x_treat
// ---------------------------------------------------------------------------
__global__ __launch_bounds__(256) void prep_x_kernel(
    const float* __restrict__ x, unsigned short* __restrict__ XFb,
    float* __restrict__ kb, float* __restrict__ out)
{
  const int b    = blockIdx.x * 4 + (threadIdx.x >> 6);
  const int lane = threadIdx.x & 63;
  const float* xr = x + (size_t)b * XCOLS;

  const float* fp = xr + 2 + lane * 8;
  float2 a0 = *(const float2*)(fp + 0);
  float2 a1 = *(const float2*)(fp + 2);
  float2 a2 = *(const float2*)(fp + 4);
  float2 a3 = *(const float2*)(fp + 6);
  u16x8 pk;
  pk[0] = f2bf(a0.x); pk[1] = f2bf(a0.y); pk[2] = f2bf(a1.x); pk[3] = f2bf(a1.y);
  pk[4] = f2bf(a2.x); pk[5] = f2bf(a2.y); pk[6] = f2bf(a3.x); pk[7] = f2bf(a3.y);
  *reinterpret_cast<u16x8*>(XFb + (size_t)b * IND_ + lane * 8) = pk;

  float t0 = xr[0], t1 = xr[1];
  if (lane < 2) out[(size_t)b * XCOLS + lane] = (lane == 0) ? t0 : t1;
  if (lane < ND) {
    int d1 = lane / 5;
    int d2 = lane - d1 * 5;
    kb[(size_t)b * ND + lane] = basis_f(t0, d1) * basis_f(t1, d2);
  }
}

// ---------------------------------------------------------------------------
// prep_w: W[i,o,d] (fp32) -> Wt[o][d*512+i] (bf16).
// Block = (32 i-rows) x (8 o).  Two LDS stages so BOTH the global read and
// the global write are coalesced.
// ---------------------------------------------------------------------------
#define PWI 32
#define PWO 8
#define PWC (PWO * ND)   // 200 columns (o_l*25 + d)
#define PWP 208          // padded float stride
#define OLS 36           // out_ls padded ushort stride

__global__ __launch_bounds__(256) void prep_w_kernel(
    const float* __restrict__ W, unsigned short* __restrict__ Wt)
{
  __shared__ float tile[PWI * PWP];            // 26.6 KB
  __shared__ unsigned short out_ls[PWC * OLS]; // 14.4 KB
  const int tid = threadIdx.x;
  const int i0  = blockIdx.x * PWI;
  const int o0  = blockIdx.y * PWO;

  // load: 32 rows x 50 float4 (contiguous 200-float runs per i-row)
  for (int idx = tid; idx < PWI * (PWC / 4); idx += 256) {
    int il = idx / (PWC / 4);
    int c4 = idx - il * (PWC / 4);
    float4 v = *(const float4*)(W + ((size_t)(i0 + il) * OUTD_ + o0) * ND + c4 * 4);
    *(float4*)&tile[il * PWP + c4 * 4] = v;
  }
  __syncthreads();

  // pack: thread c < 200 handles column c = o_l*25 + d; 4 granules of 8 i
  if (tid < PWC) {
    #pragma unroll
    for (int j = 0; j < PWI / 8; ++j) {
      u16x8 pk;
      #pragma unroll
      for (int jj = 0; jj < 8; ++jj)
        pk[jj] = f2bf(tile[(j * 8 + jj) * PWP + tid]);   // lane-consecutive: no conflict
      *reinterpret_cast<u16x8*>(&out_ls[tid * OLS + j * 8]) = pk;
    }
  }
  __syncthreads();

  // coalesced store: 800 granules; 4 consecutive lanes cover one 64B row-chunk
  for (int g = tid; g < PWC * (PWI / 8); g += 256) {
    int c  = g >> 2;          // column (o_l, d)
    int ig = g & 3;           // i-granule
    int d  = c % 25;
    int o_l = c / 25;
    u16x8 v = *reinterpret_cast<const u16x8*>(&out_ls[c * OLS + ig * 8]);
    size_t rowb = (size_t)(o0 + o_l) * KTOT + (size_t)d * IND_ + i0;
    *reinterpret_cast<u16x8*>(Wt + rowb + ig * 8) = v;
  }
}

// ---------------------------------------------------------------------------
// gemm_fused: C[o][b] = sum_k Wt[o][k] * (kb[b,d(k)]*xf[b,i(k)]), K=12800,
// split-K 4.  A staged via global_load_lds x16; B staged manually with the
// kb-scale fused (load XFb granule -> fp32 scale -> pk_bf16 -> ds_write_b128)
// into the SAME swizzled layout the MFMA readers use.  No Bp in global.
// XCD swizzle pins each o-tile's 3.27MB Wt slice to an XCD pair (<=4MB L2).
// ---------------------------------------------------------------------------
__global__ __launch_bounds__(256, 2) void gemm_fused_kernel(
    const unsigned short* __restrict__ Wt, const unsigned short* __restrict__ XFb,
    const float* __restrict__ kb, float* __restrict__ P)
{
  __shared__ unsigned short Als[BM * BK];   // 16 KB
  __shared__ unsigned short Bls[BN * BK];   // 16 KB

  const int tid  = threadIdx.x;
  const int lane = tid & 63;
  const int w    = tid >> 6;
  const int l15  = lane & 15;
  const int quad = lane >> 4;

  // 512 blocks; id%8 = XCD (round-robin heuristic). bx on a fixed XCD pair.
  const int id  = blockIdx.x;
  const int xcd = id & 7;
  const int j   = id >> 3;              // [0,64)
  const int bx  = xcd >> 1;             // o-tile [0,4)
  const int pg  = (xcd & 1) + j * 2;    // [0,128): (b-tile, split)
  const int by  = pg & 31;
  const int bz  = pg >> 5;              // split [0,4)

  const int o0 = bx * BM;
  const int b0 = by * BN;
  const int kbase = bz * (KTOT / 4);

  const int o_off = (w & 1) * 64;
  const int b_off = (w >> 1) * 64;
  const int srow  = lane >> 3;                 // 0..7 row-in-chunk
  const int sg    = lane & 7;                  // logical granule
  const int pgr   = sg ^ srow;                 // phys (swizzled) granule
  const int scol  = pgr * 8;                   // A: swizzled SOURCE col
  const int r7    = l15 & 7;

  f32x4 acc[4][4];
  #pragma unroll
  for (int i = 0; i < 4; ++i)
    #pragma unroll
    for (int jj = 0; jj < 4; ++jj) acc[i][jj] = (f32x4)0.0f;

  for (int k0 = kbase; k0 < kbase + KTOT / 4; k0 += BK) {
    const int d  = k0 >> 9;       // 64-col window lies inside one d
    const int i0 = k0 & 511;

    // A: async global->LDS (swizzle applied on the SOURCE address)
    #pragma unroll
    for (int c = 0; c < 4; ++c) {
      int chunk = w * 4 + c;
      int r = chunk * 8 + srow;
      gload_lds16(Wt + (size_t)(o0 + r) * KTOT + k0 + scol, &Als[chunk * 512]);
    }
    // B: fused scale.  lane handles (row = chunk*8+srow, granule sg).
    #pragma unroll
    for (int c = 0; c < 4; ++c) {
      int chunk = w * 4 + c;
      int row = chunk * 8 + srow;
      u16x8 v = *(const u16x8*)(XFb + (size_t)(b0 + row) * IND_ + i0 + sg * 8);
      float s = kb[(size_t)(b0 + row) * ND + d];
      u32x4 rp;
      #pragma unroll
      for (int p = 0; p < 4; ++p)
        rp[p] = pk_bf16(bf2f(v[2 * p]) * s, bf2f(v[2 * p + 1]) * s);
      *reinterpret_cast<u32x4*>(&Bls[(size_t)row * BK + pgr * 8]) = rp;
    }
    __syncthreads();

    #pragma unroll
    for (int ks = 0; ks < 2; ++ks) {
      bf16x8 af[4], bfr[4];
      #pragma unroll
      for (int mf = 0; mf < 4; ++mf) {
        int row = o_off + mf * 16 + l15;
        int g   = (ks * 4 + quad) ^ r7;
        af[mf] = *reinterpret_cast<const bf16x8*>(&Als[row * BK + g * 8]);
      }
      #pragma unroll
      for (int nf = 0; nf < 4; ++nf) {
        int row = b_off + nf * 16 + l15;
        int g   = (ks * 4 + quad) ^ r7;
        bfr[nf] = *reinterpret_cast<const bf16x8*>(&Bls[row * BK + g * 8]);
      }
      #pragma unroll
      for (int mf = 0; mf < 4; ++mf)
        #pragma unroll
        for (int nf = 0; nf < 4; ++nf)
          acc[mf][nf] = __builtin_amdgcn_mfma_f32_16x16x32_bf16(
              af[mf], bfr[nf], acc[mf][nf], 0, 0, 0);
    }
    __syncthreads();
  }

  float* Pz = P + (size_t)bz * NB * OUTD_;
  #pragma unroll
  for (int mf = 0; mf < 4; ++mf)
    #pragma unroll
    for (int nf = 0; nf < 4; ++nf) {
      int bg = b0 + b_off + nf * 16 + l15;
      int og = o0 + o_off + mf * 16 + quad * 4;
      *reinterpret_cast<f32x4*>(&Pz[(size_t)bg * OUTD_ + og]) = acc[mf][nf];
    }
}

// ---------------------------------------------------------------------------
// epilogue: out[b][2+o] = relu(sum_s P[s][b][o] + dot25(kb[b], bias[o]))
// ---------------------------------------------------------------------------
__global__ __launch_bounds__(256) void epilogue_kernel(
    const float* __restrict__ P, const float* __restrict__ kb,
    const float* __restrict__ bias, float* __restrict__ out, int S)
{
  const int idx = blockIdx.x * 256 + threadIdx.x;
  const int b = idx >> 9;
  const int o = idx & 511;
  float s = 0.0f;
  for (int zz = 0; zz < S; ++zz) s += P[(size_t)zz * (NB * OUTD_) + idx];
  const float* kr = kb + (size_t)b * ND;
  const float* br = bias + (size_t)o * ND;
  float t = 0.0f;
  #pragma unroll
  for (int d = 0; d < ND; ++d) t += kr[d] * br[d];
  s += t;
  out[(size_t)b * XCOLS + 2 + o] = s > 0.0f ? s : 0.0f;
}

// ---------------------------------------------------------------------------
extern "C" void kernel_launch(void* const* d_in, const int* in_sizes, int n_in,
                              void* d_out, int out_size, void* d_ws, size_t ws_size,
                              hipStream_t stream) {
  const float* x    = (const float*)d_in[0];   // 4096 x 514
  const float* W    = (const float*)d_in[1];   // 512 x 512 x 25
  const float* bias = (const float*)d_in[2];   // 512 x 25
  float* out = (float*)d_out;
  char* ws = (char*)d_ws;

  // ws layout (bytes): XFb 4,194,304 | Wt 13,107,200 | kb 409,600 | P 33,554,432
  const size_t xfb_off = 0;
  const size_t wt_off  = 4194304;
  const size_t kb_off  = 17301504;
  const size_t p_off   = 17711104;
  unsigned short* XFb = (unsigned short*)(ws + xfb_off);
  unsigned short* Wt  = (unsigned short*)(ws + wt_off);
  float* kb           = (float*)(ws + kb_off);
  float* P            = (float*)(ws + p_off);

  prep_x_kernel<<<NB / 4, 256, 0, stream>>>(x, XFb, kb, out);
  prep_w_kernel<<<dim3(IND_ / PWI, OUTD_ / PWO), 256, 0, stream>>>(W, Wt);
  gemm_fused_kernel<<<512, 256, 0, stream>>>(Wt, XFb, kb, P);
  epilogue_kernel<<<(NB * OUTD_) / 256, 256, 0, stream>>>(P, kb, bias, out, 4);
}